// Round 15
// baseline (146.816 us; speedup 1.0000x reference)
//
#include <hip/hip_runtime.h>
#include <hip/hip_bf16.h>

// FastCapsNetMulti via bf16 MFMA — r15 = r12 pipeline (best-known-good, 69us)
// + two DIAGNOSTIC kernels (x6 phase repeats) to attribute the conv's ~36us:
//   diag_stage: xb2->LDS staging phase only, x6
//   diag_mfma : 9-tap x 5-kc MFMA loop only (A=LDS, B=global), x6
// r15 fix vs r14: diag scratch moved to VIRGIN ws after capsb (r14 aliased it
// onto xb2 and corrupted the conv input -> NaN).
// B=64, H=W=32, N=8192, classes=10, class_dim=16, cap_dim=8.

typedef __attribute__((ext_vector_type(8))) short bf16x8s;
typedef __attribute__((ext_vector_type(4))) float f32x4;

__device__ inline short f2bf(float f) {
    __hip_bfloat16 h = __float2bfloat16(f);
    return *reinterpret_cast<short*>(&h);
}

#define XB_B (20 * 1156 * 8)   // elements per b in xb2 ([cb][34][34][8])
#define PLANE_SH 1096          // 4*34*8 + 8 pad: 16B-aligned stride

// ---------------- k1: prep (weights + activations + SAR conv) ----------------
__global__ __launch_bounds__(256) void prep_kernel(
        const float* __restrict__ wh, short* __restrict__ wtb2,
        const float* __restrict__ x_hsi, short* __restrict__ xb2,
        const float* __restrict__ x_sar, const float* __restrict__ wsar,
        const float* __restrict__ bs, short* __restrict__ capsb) {
    __shared__ union {
        short tile[144][33];    // x-pass transpose
        float wt_lds[1152];     // SAR weights [cin][tap][oc]
    } sm;
    int t = threadIdx.x;

    if (blockIdx.x < 180) {
        int idx = blockIdx.x * 256 + t;       // < 9*20*32*8 = 46080
        int tap = idx / 5120;
        int r2 = idx - tap * 5120;
        int cb = r2 >> 8;
        int oc = (r2 >> 3) & 31;
        int d = r2 & 7;
        int ch = cb * 8 + d;
        short v = 0;
        if (ch < 144) v = f2bf(wh[(oc * 144 + ch) * 9 + tap]);
        wtb2[idx] = v;
        return;
    }

    if (blockIdx.x >= 2356) {
        // ---- SAR conv: XCD-swizzled (256 = 8 xcd x 32 slots) ----------------
        for (int i = t; i < 1152; i += 256) {
            int oc = i / 36;
            int r = i - oc * 36;
            int cin = r / 9;
            int tap = r - cin * 9;
            sm.wt_lds[cin * 288 + tap * 32 + oc] = wsar[i];
        }
        __syncthreads();

        int blk = blockIdx.x - 2356;          // 0..255
        int xcd = blk & 7;
        int slot = blk >> 3;                  // 0..31
        int b = xcd + ((slot >> 2) << 3);
        int q = slot & 3;
        int p = q * 256 + t;                  // pixel 0..1023
        int y = p >> 5, x = p & 31;

        float acc[32];
        #pragma unroll
        for (int oc = 0; oc < 32; ++oc) acc[oc] = bs[oc];

        for (int cin = 0; cin < 4; ++cin) {
            const float* xc = x_sar + ((size_t)b * 4 + cin) * 1024;
            const float* wc = &sm.wt_lds[cin * 288];
            #pragma unroll
            for (int ky = 0; ky < 3; ++ky) {
                int iy = y + ky - 1;
                bool rowok = (iy >= 0) && (iy < 32);
                const float* xrow = xc + iy * 32;
                float v0 = (rowok && x > 0)  ? xrow[x - 1] : 0.0f;
                float v1 = rowok             ? xrow[x]     : 0.0f;
                float v2 = (rowok && x < 31) ? xrow[x + 1] : 0.0f;
                const float* wk = wc + ky * 96;
                #pragma unroll
                for (int oc = 0; oc < 32; ++oc)
                    acc[oc] += v0 * wk[oc] + v1 * wk[32 + oc] + v2 * wk[64 + oc];
            }
        }

        #pragma unroll
        for (int cap = 0; cap < 4; ++cap) {
            float sq = 0.0f;
            #pragma unroll
            for (int d = 0; d < 8; ++d) sq += acc[cap * 8 + d] * acc[cap * 8 + d];
            float scale = sq / ((1.0f + sq) * sqrtf(sq + 1e-8f));
            int n = 4096 + p * 4 + cap;
            bf16x8s o;
            #pragma unroll
            for (int d = 0; d < 8; ++d) o[d] = f2bf(acc[cap * 8 + d] * scale);
            *(bf16x8s*)(capsb + ((size_t)b * 8192 + n) * 8) = o;
        }
        return;
    }

    // ---- x-pass: XCD-swizzled (2176 = 8 xcd x 272 slots) --------------------
    int blk = blockIdx.x - 180;               // 0..2175
    int xcd = blk & 7;
    int slot = blk >> 3;                      // 0..271
    int b = xcd + ((slot / 34) << 3);
    int y_o = slot % 34;
    bool yok = (y_o >= 1) && (y_o <= 32);
    int iy = y_o - 1;
    if (yok) {
        for (int base = 0; base < 144; base += 8) {
            int ch = base + (t >> 5), x = t & 31;
            sm.tile[ch][x] = f2bf(x_hsi[(((size_t)b * 144 + ch) * 32 + iy) * 32 + x]);
        }
    }
    __syncthreads();
    short* dstb = xb2 + (size_t)b * XB_B;
    for (int item = t; item < 680; item += 256) {   // 20 cb x 34 xx, 16B each
        int cb = item / 34;
        int xx = item - cb * 34;
        bf16x8s v = {0, 0, 0, 0, 0, 0, 0, 0};
        if (yok && xx >= 1 && xx <= 32 && cb < 18) {
            int x = xx - 1;
            #pragma unroll
            for (int d = 0; d < 8; ++d) v[d] = sm.tile[cb * 8 + d][x];
        }
        *(bf16x8s*)(dstb + ((size_t)(cb * 34 + y_o) * 34 + xx) * 8) = v;
    }
}

// ---------------- DIAG A: staging phase only, x6 -----------------------------
__global__ __launch_bounds__(256) void diag_stage_kernel(
        const short* __restrict__ xb2, float* __restrict__ scratch) {
    __shared__ short xs[20 * PLANE_SH];
    int t = threadIdx.x;
    int bid = blockIdx.x;
    int xcd = bid & 7;
    int slot = bid >> 3;
    int b = xcd + ((slot >> 4) << 3);
    const short* srcb = xb2 + (size_t)b * XB_B;
    #pragma unroll 1
    for (int rep = 0; rep < 6; ++rep) {
        int y0 = (((slot & 15) + rep * 4) & 15) << 1;
        const short* src = srcb + y0 * 272;
        for (int i = t; i < 2720; i += 256) {
            int cb = i / 136;
            int rem = i - cb * 136;
            bf16x8s v = *(const bf16x8s*)(src + (size_t)cb * 9248 + rem * 8);
            *(bf16x8s*)&xs[cb * PLANE_SH + rem * 8] = v;
        }
        __syncthreads();
    }
    float s = (float)xs[t] + (float)xs[t + 4096] + (float)xs[t + 8192]
            + (float)xs[t + 16384];
    scratch[bid * 256 + t] = s;
}

// ---------------- DIAG B: MFMA loop only (A=LDS, B=global), x6 ---------------
__global__ __launch_bounds__(256) void diag_mfma_kernel(
        const short* __restrict__ wtb2, float* __restrict__ scratch) {
    __shared__ short xs[20 * PLANE_SH];
    int t = threadIdx.x;
    int bid = blockIdx.x;
    for (int i = t; i < 2740; i += 256) {     // fill LDS (values irrelevant)
        if (i * 8 + 8 <= 20 * PLANE_SH)
            *(bf16x8s*)&xs[i * 8] = (bf16x8s){256, 257, 258, 259, 260, 261, 262, 263};
    }
    __syncthreads();

    int l = t & 63;
    int wv = t >> 6;
    int wr = wv >> 1;
    int xh = wv & 1;
    int l15 = l & 15, lhi = l >> 4;

    f32x4 acc0 = {0.f, 0.f, 0.f, 0.f};
    f32x4 acc1 = {0.f, 0.f, 0.f, 0.f};

    #pragma unroll 1
    for (int rep = 0; rep < 6; ++rep) {
        #pragma unroll
        for (int tap = 0; tap < 9; ++tap) {
            int dy = tap / 3, dx = tap % 3;
            int arow = ((wr + dy) * 34 + xh * 16 + l15 + dx) * 8;
            #pragma unroll
            for (int kc = 0; kc < 5; ++kc) {
                int plane = kc * 4 + lhi;
                bf16x8s a  = *(const bf16x8s*)&xs[plane * PLANE_SH + arow];
                const short* wa = wtb2 + ((size_t)(tap * 20 + plane) * 32 + l15) * 8;
                bf16x8s b0 = *(const bf16x8s*)wa;
                bf16x8s b1 = *(const bf16x8s*)(wa + 128);
                acc0 = __builtin_amdgcn_mfma_f32_16x16x32_bf16(a, b0, acc0, 0, 0, 0);
                acc1 = __builtin_amdgcn_mfma_f32_16x16x32_bf16(a, b1, acc1, 0, 0, 0);
            }
        }
        __syncthreads();
    }
    float s = acc0[0] + acc0[1] + acc0[2] + acc0[3]
            + acc1[0] + acc1[1] + acc1[2] + acc1[3];
    scratch[bid * 256 + t] = s;
}

// ---------------- k2: HSI conv via MFMA (r12, unchanged) ---------------------
__global__ __launch_bounds__(256) void conv_hsi_kernel(
        const short* __restrict__ xb2, const short* __restrict__ wtb2,
        const float* __restrict__ bh, short* __restrict__ capsb) {
    __shared__ union {
        short xs[20 * PLANE_SH];   // 43840 B
        float ct[64][33];          // 8448 B
    } sm;
    int t = threadIdx.x;
    int bid = blockIdx.x;
    int xcd = bid & 7;
    int slot = bid >> 3;                      // 0..127
    int b = xcd + ((slot >> 4) << 3);
    int y0 = (slot & 15) << 1;                // output rows y0, y0+1

    const short* src = xb2 + (size_t)b * XB_B + y0 * 272;
    for (int i = t; i < 2720; i += 256) {
        int cb = i / 136;
        int rem = i - cb * 136;
        bf16x8s v = *(const bf16x8s*)(src + (size_t)cb * 9248 + rem * 8);
        *(bf16x8s*)&sm.xs[cb * PLANE_SH + rem * 8] = v;
    }
    __syncthreads();

    int l = t & 63;
    int wv = t >> 6;
    int wr = wv >> 1;
    int xh = wv & 1;
    int l15 = l & 15, lhi = l >> 4;

    f32x4 acc0 = {0.f, 0.f, 0.f, 0.f};
    f32x4 acc1 = {0.f, 0.f, 0.f, 0.f};

    #pragma unroll
    for (int tap = 0; tap < 9; ++tap) {
        int dy = tap / 3, dx = tap % 3;
        int arow = ((wr + dy) * 34 + xh * 16 + l15 + dx) * 8;
        #pragma unroll
        for (int kc = 0; kc < 5; ++kc) {
            int plane = kc * 4 + lhi;
            bf16x8s a = *(const bf16x8s*)&sm.xs[plane * PLANE_SH + arow];
            const short* wa = wtb2 + ((size_t)(tap * 20 + plane) * 32 + l15) * 8;
            bf16x8s b0 = *(const bf16x8s*)wa;
            bf16x8s b1 = *(const bf16x8s*)(wa + 128);   // +16 oc
            acc0 = __builtin_amdgcn_mfma_f32_16x16x32_bf16(a, b0, acc0, 0, 0, 0);
            acc1 = __builtin_amdgcn_mfma_f32_16x16x32_bf16(a, b1, acc1, 0, 0, 0);
        }
    }
    __syncthreads();

    #pragma unroll
    for (int r = 0; r < 4; ++r) {
        int px = wr * 32 + xh * 16 + lhi * 4 + r;
        sm.ct[px][l15] = acc0[r];
        sm.ct[px][16 + l15] = acc1[r];
    }
    __syncthreads();

    int p = t >> 2;
    int cap = t & 3;
    float s[8];
    float sq = 0.0f;
    #pragma unroll
    for (int d = 0; d < 8; ++d) {
        s[d] = sm.ct[p][cap * 8 + d] + bh[cap * 8 + d];
        sq += s[d] * s[d];
    }
    float scale = sq / ((1.0f + sq) * sqrtf(sq + 1e-8f));
    int pix = (y0 + (p >> 5)) * 32 + (p & 31);
    int n = pix * 4 + cap;
    bf16x8s o;
    #pragma unroll
    for (int d = 0; d < 8; ++d) o[d] = f2bf(s[d] * scale);
    *(bf16x8s*)(capsb + ((size_t)b * 8192 + n) * 8) = o;
}

// ---------------- k3: routing via MFMA (r12, unchanged) ----------------------
__global__ __launch_bounds__(256) void routing_mfma_kernel(
        const short* __restrict__ capsb, const float* __restrict__ W,
        float* __restrict__ partials) {
    __shared__ union {
        short ct[64][64][8];    // 65536 B
        float red[4][64][34];
    } sm;
    int t = threadIdx.x;
    int kc = blockIdx.x;
    int ntp = blockIdx.y;
    int n0 = kc * 64;

    {
        int b = t >> 2;
        int ng = t & 3;
        const short* src = capsb + ((size_t)b * 8192 + n0 + ng * 16) * 8;
        #pragma unroll
        for (int i = 0; i < 16; ++i) {
            bf16x8s v = *(const bf16x8s*)(src + i * 8);
            *(bf16x8s*)&sm.ct[ng * 16 + i][b][0] = v;
        }
    }
    __syncthreads();

    int l = t & 63;
    int wv = t >> 6;
    int l15 = l & 15, lhi = l >> 4;

    f32x4 acc[2][4];
    #pragma unroll
    for (int a = 0; a < 2; ++a)
        #pragma unroll
        for (int m = 0; m < 4; ++m) acc[a][m] = (f32x4){0.f, 0.f, 0.f, 0.f};

    #pragma unroll
    for (int ks = 0; ks < 4; ++ks) {
        int nl = (wv * 4 + ks) * 4 + lhi;
        int n = n0 + nl;
        const float* wp = W + ((size_t)n * 160 + ntp * 32 + l15) * 8;
        union { short s[8]; bf16x8s v; } bu[2];
        #pragma unroll
        for (int ntl = 0; ntl < 2; ++ntl) {
            const float* wq = wp + (size_t)ntl * 128;
            float4 w0 = *(const float4*)wq;
            float4 w1 = *(const float4*)(wq + 4);
            bu[ntl].s[0] = f2bf(w0.x); bu[ntl].s[1] = f2bf(w0.y);
            bu[ntl].s[2] = f2bf(w0.z); bu[ntl].s[3] = f2bf(w0.w);
            bu[ntl].s[4] = f2bf(w1.x); bu[ntl].s[5] = f2bf(w1.y);
            bu[ntl].s[6] = f2bf(w1.z); bu[ntl].s[7] = f2bf(w1.w);
        }
        bf16x8s af[4];
        #pragma unroll
        for (int mt = 0; mt < 4; ++mt)
            af[mt] = *(const bf16x8s*)&sm.ct[nl][mt * 16 + l15][0];
        #pragma unroll
        for (int ntl = 0; ntl < 2; ++ntl)
            #pragma unroll
            for (int mt = 0; mt < 4; ++mt)
                acc[ntl][mt] = __builtin_amdgcn_mfma_f32_16x16x32_bf16(
                    af[mt], bu[ntl].v, acc[ntl][mt], 0, 0, 0);
    }
    __syncthreads();

    #pragma unroll
    for (int ntl = 0; ntl < 2; ++ntl)
        #pragma unroll
        for (int mt = 0; mt < 4; ++mt)
            #pragma unroll
            for (int r = 0; r < 4; ++r)
                sm.red[wv][mt * 16 + lhi * 4 + r][ntl * 16 + l15] = acc[ntl][mt][r];
    __syncthreads();

    for (int idx = t; idx < 2048; idx += 256) {
        int b = idx >> 5, cjl = idx & 31;
        float sum = sm.red[0][b][cjl] + sm.red[1][b][cjl]
                  + sm.red[2][b][cjl] + sm.red[3][b][cjl];
        partials[(((size_t)kc * 5 + ntp) * 64 + b) * 32 + cjl] = sum;
    }
}

// ---------------- k4: final reduce + squash + norm ---------------------------
__global__ __launch_bounds__(256) void finalize_kernel(
        const float* __restrict__ partials, float* __restrict__ out) {
    __shared__ float s_sh[160];
    int t = threadIdx.x;
    int b = blockIdx.x;
    if (t < 160) {
        int ntp = t >> 5, cjl = t & 31;
        float s = 0.0f;
        #pragma unroll 8
        for (int kc = 0; kc < 128; ++kc)
            s += partials[(((size_t)kc * 5 + ntp) * 64 + b) * 32 + cjl];
        s_sh[ntp * 32 + cjl] = s * (1.0f / 8192.0f);
    }
    __syncthreads();
    if (t < 10) {
        float sq = 0.0f;
        #pragma unroll
        for (int j = 0; j < 16; ++j) {
            float v = s_sh[t * 16 + j];
            sq += v * v;
        }
        float scale = sq / ((1.0f + sq) * sqrtf(sq + 1e-8f));
        out[b * 10 + t] = sqrtf(sq) * scale;
    }
}

extern "C" void kernel_launch(void* const* d_in, const int* in_sizes, int n_in,
                              void* d_out, int out_size, void* d_ws, size_t ws_size,
                              hipStream_t stream) {
    const float* x_hsi = (const float*)d_in[0];   // [64,144,32,32]
    const float* x_sar = (const float*)d_in[1];   // [64,4,32,32]
    const float* wh    = (const float*)d_in[2];   // [32,144,3,3]
    const float* bh    = (const float*)d_in[3];   // [32]
    const float* wsar  = (const float*)d_in[4];   // [32,4,3,3]
    const float* bs    = (const float*)d_in[5];   // [32]
    const float* W     = (const float*)d_in[6];   // [8192,10,16,8]
    float* out = (float*)d_out;                   // [64,10]

    char* ws = (char*)d_ws;
    short* wtb2     = (short*)(ws + 0);           // 92160 B
    short* xb2      = (short*)(ws + 131072);      // 23674880 B (live until conv done!)
    // partials aliases xb2 ONLY for routing (runs after conv has consumed xb2)
    float* partials = (float*)(ws + 131072);      // 128*5*64*32*4 = 5242880 B
    short* capsb    = (short*)(ws + 23805952);    // 8388608 B
    // diag scratch in VIRGIN region after capsb (never aliases live data)
    float* scratchA = (float*)(ws + 32194560);    // 1 MB
    float* scratchB = (float*)(ws + 33243136);    // 1 MB

    prep_kernel<<<2612, 256, 0, stream>>>(wh, wtb2, x_hsi, xb2, x_sar, wsar, bs, capsb);

    // ---- diagnostics (read-only on xb2/wtb2; write only virgin scratch) -----
    diag_stage_kernel<<<1024, 256, 0, stream>>>(xb2, scratchA);
    diag_mfma_kernel<<<1024, 256, 0, stream>>>(wtb2, scratchB);

    conv_hsi_kernel<<<1024, 256, 0, stream>>>(xb2, wtb2, bh, capsb);

    routing_mfma_kernel<<<dim3(128, 5), 256, 0, stream>>>(capsb, W, partials);

    finalize_kernel<<<64, 256, 0, stream>>>(partials, out);
}

// Round 16
// 70.353 us; speedup vs baseline: 2.0868x; 2.0868x over previous
//
#include <hip/hip_runtime.h>
#include <hip/hip_bf16.h>

// FastCapsNetMulti via bf16 MFMA, 4 launches. r16 = r12 + conv B-prefetch:
// double-buffered register prefetch of the next tap's 10 B-fragments (all
// compile-time indices), issued before the current tap's MFMAs; tap-0 B-loads
// issued before A-staging so they overlap it. Kills the serialized ~200cyc
// L2 wait per (tap,kc) step that r15's diagnostics isolated.
//  k1 prep: blocks 0..179 wtb2; 180..2355 xb2 (XCD-swizzled); 2356.. SAR conv
//  k2 conv_hsi: 1024 blocks XCD-swizzled, LDS A + register-pipelined global B
//  k3 routing: grid(128,5)   k4 finalize
// B=64, H=W=32, N=8192, classes=10, class_dim=16, cap_dim=8.

typedef __attribute__((ext_vector_type(8))) short bf16x8s;
typedef __attribute__((ext_vector_type(4))) float f32x4;

__device__ inline short f2bf(float f) {
    __hip_bfloat16 h = __float2bfloat16(f);
    return *reinterpret_cast<short*>(&h);
}

#define XB_B (20 * 1156 * 8)   // elements per b in xb2 ([cb][34][34][8])
#define PLANE_SH 1096          // 4*34*8 + 8 pad: 16B-aligned stride

// ---------------- k1: prep (weights + activations + SAR conv) ----------------
__global__ __launch_bounds__(256) void prep_kernel(
        const float* __restrict__ wh, short* __restrict__ wtb2,
        const float* __restrict__ x_hsi, short* __restrict__ xb2,
        const float* __restrict__ x_sar, const float* __restrict__ wsar,
        const float* __restrict__ bs, short* __restrict__ capsb) {
    __shared__ union {
        short tile[144][33];    // x-pass transpose
        float wt_lds[1152];     // SAR weights [cin][tap][oc]
    } sm;
    int t = threadIdx.x;

    if (blockIdx.x < 180) {
        int idx = blockIdx.x * 256 + t;       // < 9*20*32*8 = 46080
        int tap = idx / 5120;
        int r2 = idx - tap * 5120;
        int cb = r2 >> 8;
        int oc = (r2 >> 3) & 31;
        int d = r2 & 7;
        int ch = cb * 8 + d;
        short v = 0;
        if (ch < 144) v = f2bf(wh[(oc * 144 + ch) * 9 + tap]);
        wtb2[idx] = v;
        return;
    }

    if (blockIdx.x >= 2356) {
        // ---- SAR conv: XCD-swizzled (256 = 8 xcd x 32 slots) ----------------
        for (int i = t; i < 1152; i += 256) {
            int oc = i / 36;
            int r = i - oc * 36;
            int cin = r / 9;
            int tap = r - cin * 9;
            sm.wt_lds[cin * 288 + tap * 32 + oc] = wsar[i];
        }
        __syncthreads();

        int blk = blockIdx.x - 2356;          // 0..255
        int xcd = blk & 7;
        int slot = blk >> 3;                  // 0..31
        int b = xcd + ((slot >> 2) << 3);
        int q = slot & 3;
        int p = q * 256 + t;                  // pixel 0..1023
        int y = p >> 5, x = p & 31;

        float acc[32];
        #pragma unroll
        for (int oc = 0; oc < 32; ++oc) acc[oc] = bs[oc];

        for (int cin = 0; cin < 4; ++cin) {
            const float* xc = x_sar + ((size_t)b * 4 + cin) * 1024;
            const float* wc = &sm.wt_lds[cin * 288];
            #pragma unroll
            for (int ky = 0; ky < 3; ++ky) {
                int iy = y + ky - 1;
                bool rowok = (iy >= 0) && (iy < 32);
                const float* xrow = xc + iy * 32;
                float v0 = (rowok && x > 0)  ? xrow[x - 1] : 0.0f;
                float v1 = rowok             ? xrow[x]     : 0.0f;
                float v2 = (rowok && x < 31) ? xrow[x + 1] : 0.0f;
                const float* wk = wc + ky * 96;
                #pragma unroll
                for (int oc = 0; oc < 32; ++oc)
                    acc[oc] += v0 * wk[oc] + v1 * wk[32 + oc] + v2 * wk[64 + oc];
            }
        }

        #pragma unroll
        for (int cap = 0; cap < 4; ++cap) {
            float sq = 0.0f;
            #pragma unroll
            for (int d = 0; d < 8; ++d) sq += acc[cap * 8 + d] * acc[cap * 8 + d];
            float scale = sq / ((1.0f + sq) * sqrtf(sq + 1e-8f));
            int n = 4096 + p * 4 + cap;
            bf16x8s o;
            #pragma unroll
            for (int d = 0; d < 8; ++d) o[d] = f2bf(acc[cap * 8 + d] * scale);
            *(bf16x8s*)(capsb + ((size_t)b * 8192 + n) * 8) = o;
        }
        return;
    }

    // ---- x-pass: XCD-swizzled (2176 = 8 xcd x 272 slots) --------------------
    int blk = blockIdx.x - 180;               // 0..2175
    int xcd = blk & 7;
    int slot = blk >> 3;                      // 0..271
    int b = xcd + ((slot / 34) << 3);
    int y_o = slot % 34;
    bool yok = (y_o >= 1) && (y_o <= 32);
    int iy = y_o - 1;
    if (yok) {
        for (int base = 0; base < 144; base += 8) {
            int ch = base + (t >> 5), x = t & 31;
            sm.tile[ch][x] = f2bf(x_hsi[(((size_t)b * 144 + ch) * 32 + iy) * 32 + x]);
        }
    }
    __syncthreads();
    short* dstb = xb2 + (size_t)b * XB_B;
    for (int item = t; item < 680; item += 256) {   // 20 cb x 34 xx, 16B each
        int cb = item / 34;
        int xx = item - cb * 34;
        bf16x8s v = {0, 0, 0, 0, 0, 0, 0, 0};
        if (yok && xx >= 1 && xx <= 32 && cb < 18) {
            int x = xx - 1;
            #pragma unroll
            for (int d = 0; d < 8; ++d) v[d] = sm.tile[cb * 8 + d][x];
        }
        *(bf16x8s*)(dstb + ((size_t)(cb * 34 + y_o) * 34 + xx) * 8) = v;
    }
}

// ---------------- k2: HSI conv via MFMA + register B-pipeline ----------------
// 1024 blocks XCD-swizzled. A staged in LDS (PLANE_SH=1096: aligned b128).
// B: double-buffered register prefetch — tap0's 10 fragments load before the
// A-staging loop; tap t+1's load before tap t's MFMAs. All buffer indices are
// compile-time (fully unrolled tap loop, tap&1 selection).
__global__ __launch_bounds__(256) void conv_hsi_kernel(
        const short* __restrict__ xb2, const short* __restrict__ wtb2,
        const float* __restrict__ bh, short* __restrict__ capsb) {
    __shared__ union {
        short xs[20 * PLANE_SH];   // 43840 B
        float ct[64][33];          // 8448 B
    } sm;
    int t = threadIdx.x;
    int bid = blockIdx.x;
    int xcd = bid & 7;
    int slot = bid >> 3;                      // 0..127
    int b = bid < 0 ? 0 : (xcd + ((slot >> 4) << 3));
    int y0 = (slot & 15) << 1;                // output rows y0, y0+1

    int l = t & 63;
    int wv = t >> 6;
    int wr = wv >> 1;            // output row within block
    int xh = wv & 1;             // x half
    int l15 = l & 15, lhi = l >> 4;

    // ---- issue tap-0 B prefetch BEFORE staging (overlaps) -------------------
    const short* wbase = wtb2 + ((size_t)(lhi * 32) + l15) * 8;   // + tap*20*256 + kc*4*256
    bf16x8s b0buf[2][5], b1buf[2][5];
    #pragma unroll
    for (int kc = 0; kc < 5; ++kc) {
        const short* wa = wbase + (size_t)kc * 1024;              // kc*4 planes * 256
        b0buf[0][kc] = *(const bf16x8s*)wa;
        b1buf[0][kc] = *(const bf16x8s*)(wa + 128);
    }

    // ---- stage A: pure bf16 copy, 16B/lane ----------------------------------
    const short* src = xb2 + (size_t)b * XB_B + y0 * 272;
    for (int i = t; i < 2720; i += 256) {
        int cb = i / 136;
        int rem = i - cb * 136;
        bf16x8s v = *(const bf16x8s*)(src + (size_t)cb * 9248 + rem * 8);
        *(bf16x8s*)&sm.xs[cb * PLANE_SH + rem * 8] = v;
    }
    __syncthreads();

    f32x4 acc0 = {0.f, 0.f, 0.f, 0.f};
    f32x4 acc1 = {0.f, 0.f, 0.f, 0.f};

    #pragma unroll
    for (int tap = 0; tap < 9; ++tap) {
        const int cur = tap & 1, nxt = cur ^ 1;
        if (tap < 8) {   // prefetch next tap's B while this tap computes
            #pragma unroll
            for (int kc = 0; kc < 5; ++kc) {
                const short* wa = wbase + (size_t)(tap + 1) * 5120 + (size_t)kc * 1024;
                b0buf[nxt][kc] = *(const bf16x8s*)wa;
                b1buf[nxt][kc] = *(const bf16x8s*)(wa + 128);
            }
        }
        int dy = tap / 3, dx = tap % 3;
        int arow = ((wr + dy) * 34 + xh * 16 + l15 + dx) * 8;
        #pragma unroll
        for (int kc = 0; kc < 5; ++kc) {
            int plane = kc * 4 + lhi;
            bf16x8s a = *(const bf16x8s*)&sm.xs[plane * PLANE_SH + arow];
            acc0 = __builtin_amdgcn_mfma_f32_16x16x32_bf16(a, b0buf[cur][kc], acc0, 0, 0, 0);
            acc1 = __builtin_amdgcn_mfma_f32_16x16x32_bf16(a, b1buf[cur][kc], acc1, 0, 0, 0);
        }
    }
    __syncthreads();   // xs reads done before ct overwrites

    #pragma unroll
    for (int r = 0; r < 4; ++r) {
        int px = wr * 32 + xh * 16 + lhi * 4 + r;
        sm.ct[px][l15] = acc0[r];
        sm.ct[px][16 + l15] = acc1[r];
    }
    __syncthreads();

    // ---- epilogue: 256 capsules (64 px x 4 caps), 1 per thread --------------
    int p = t >> 2;              // local pixel 0..63
    int cap = t & 3;
    float s[8];
    float sq = 0.0f;
    #pragma unroll
    for (int d = 0; d < 8; ++d) {
        s[d] = sm.ct[p][cap * 8 + d] + bh[cap * 8 + d];
        sq += s[d] * s[d];
    }
    float scale = sq / ((1.0f + sq) * sqrtf(sq + 1e-8f));
    int pix = (y0 + (p >> 5)) * 32 + (p & 31);
    int n = pix * 4 + cap;
    bf16x8s o;
    #pragma unroll
    for (int d = 0; d < 8; ++d) o[d] = f2bf(s[d] * scale);
    *(bf16x8s*)(capsb + ((size_t)b * 8192 + n) * 8) = o;
}

// ---------------- k3: routing via MFMA ---------------------------------------
// grid (kc 128) x (ntp 5). Stage caps[b][kc*64 .. +64] -> LDS [n][b][8]
// (transpose on write), 16 K-steps (4 per wave), 2 cj-tiles per block.
__global__ __launch_bounds__(256) void routing_mfma_kernel(
        const short* __restrict__ capsb, const float* __restrict__ W,
        float* __restrict__ partials) {
    __shared__ union {
        short ct[64][64][8];    // 65536 B
        float red[4][64][34];
    } sm;
    int t = threadIdx.x;
    int kc = blockIdx.x;
    int ntp = blockIdx.y;
    int n0 = kc * 64;

    {
        int b = t >> 2;
        int ng = t & 3;
        const short* src = capsb + ((size_t)b * 8192 + n0 + ng * 16) * 8;
        #pragma unroll
        for (int i = 0; i < 16; ++i) {
            bf16x8s v = *(const bf16x8s*)(src + i * 8);
            *(bf16x8s*)&sm.ct[ng * 16 + i][b][0] = v;
        }
    }
    __syncthreads();

    int l = t & 63;
    int wv = t >> 6;
    int l15 = l & 15, lhi = l >> 4;

    f32x4 acc[2][4];
    #pragma unroll
    for (int a = 0; a < 2; ++a)
        #pragma unroll
        for (int m = 0; m < 4; ++m) acc[a][m] = (f32x4){0.f, 0.f, 0.f, 0.f};

    #pragma unroll
    for (int ks = 0; ks < 4; ++ks) {
        int nl = (wv * 4 + ks) * 4 + lhi;
        int n = n0 + nl;
        const float* wp = W + ((size_t)n * 160 + ntp * 32 + l15) * 8;
        union { short s[8]; bf16x8s v; } bu[2];
        #pragma unroll
        for (int ntl = 0; ntl < 2; ++ntl) {
            const float* wq = wp + (size_t)ntl * 128;
            float4 w0 = *(const float4*)wq;
            float4 w1 = *(const float4*)(wq + 4);
            bu[ntl].s[0] = f2bf(w0.x); bu[ntl].s[1] = f2bf(w0.y);
            bu[ntl].s[2] = f2bf(w0.z); bu[ntl].s[3] = f2bf(w0.w);
            bu[ntl].s[4] = f2bf(w1.x); bu[ntl].s[5] = f2bf(w1.y);
            bu[ntl].s[6] = f2bf(w1.z); bu[ntl].s[7] = f2bf(w1.w);
        }
        bf16x8s af[4];
        #pragma unroll
        for (int mt = 0; mt < 4; ++mt)
            af[mt] = *(const bf16x8s*)&sm.ct[nl][mt * 16 + l15][0];
        #pragma unroll
        for (int ntl = 0; ntl < 2; ++ntl)
            #pragma unroll
            for (int mt = 0; mt < 4; ++mt)
                acc[ntl][mt] = __builtin_amdgcn_mfma_f32_16x16x32_bf16(
                    af[mt], bu[ntl].v, acc[ntl][mt], 0, 0, 0);
    }
    __syncthreads();

    #pragma unroll
    for (int ntl = 0; ntl < 2; ++ntl)
        #pragma unroll
        for (int mt = 0; mt < 4; ++mt)
            #pragma unroll
            for (int r = 0; r < 4; ++r)
                sm.red[wv][mt * 16 + lhi * 4 + r][ntl * 16 + l15] = acc[ntl][mt][r];
    __syncthreads();

    for (int idx = t; idx < 2048; idx += 256) {
        int b = idx >> 5, cjl = idx & 31;
        float sum = sm.red[0][b][cjl] + sm.red[1][b][cjl]
                  + sm.red[2][b][cjl] + sm.red[3][b][cjl];
        partials[(((size_t)kc * 5 + ntp) * 64 + b) * 32 + cjl] = sum;
    }
}

// ---------------- k4: final reduce + squash + norm ---------------------------
__global__ __launch_bounds__(256) void finalize_kernel(
        const float* __restrict__ partials, float* __restrict__ out) {
    __shared__ float s_sh[160];
    int t = threadIdx.x;
    int b = blockIdx.x;
    if (t < 160) {
        int ntp = t >> 5, cjl = t & 31;
        float s = 0.0f;
        #pragma unroll 8
        for (int kc = 0; kc < 128; ++kc)
            s += partials[(((size_t)kc * 5 + ntp) * 64 + b) * 32 + cjl];
        s_sh[ntp * 32 + cjl] = s * (1.0f / 8192.0f);
    }
    __syncthreads();
    if (t < 10) {
        float sq = 0.0f;
        #pragma unroll
        for (int j = 0; j < 16; ++j) {
            float v = s_sh[t * 16 + j];
            sq += v * v;
        }
        float scale = sq / ((1.0f + sq) * sqrtf(sq + 1e-8f));
        out[b * 10 + t] = sqrtf(sq) * scale;
    }
}

extern "C" void kernel_launch(void* const* d_in, const int* in_sizes, int n_in,
                              void* d_out, int out_size, void* d_ws, size_t ws_size,
                              hipStream_t stream) {
    const float* x_hsi = (const float*)d_in[0];   // [64,144,32,32]
    const float* x_sar = (const float*)d_in[1];   // [64,4,32,32]
    const float* wh    = (const float*)d_in[2];   // [32,144,3,3]
    const float* bh    = (const float*)d_in[3];   // [32]
    const float* wsar  = (const float*)d_in[4];   // [32,4,3,3]
    const float* bs    = (const float*)d_in[5];   // [32]
    const float* W     = (const float*)d_in[6];   // [8192,10,16,8]
    float* out = (float*)d_out;                   // [64,10]

    char* ws = (char*)d_ws;
    short* wtb2     = (short*)(ws + 0);           // 92160 B
    short* xb2      = (short*)(ws + 131072);      // 23674880 B
    // partials aliases xb2 (xb2 dead once conv_hsi completes; same-stream order)
    float* partials = (float*)(ws + 131072);      // 128*5*64*32*4 = 5242880 B
    short* capsb    = (short*)(ws + 23805952);    // 8388608 B

    prep_kernel<<<2612, 256, 0, stream>>>(wh, wtb2, x_hsi, xb2, x_sar, wsar, bs, capsb);

    conv_hsi_kernel<<<1024, 256, 0, stream>>>(xb2, wtb2, bh, capsb);

    routing_mfma_kernel<<<dim3(128, 5), 256, 0, stream>>>(capsb, W, partials);

    finalize_kernel<<<64, 256, 0, stream>>>(partials, out);
}